// Round 11
// baseline (62.730 us; speedup 1.0000x reference)
//
#include <hip/hip_runtime.h>
#include <hip/hip_bf16.h>

#define TT 4
#define BB 64
#define CC 64
#define PP 1024
#define NN 256
#define EE 8

// 1/sqrt(1+1e-5)
#define RSQ 0.99999500003749975f

typedef __attribute__((ext_vector_type(8))) short short8;
typedef __attribute__((ext_vector_type(4))) float f32x4;

static __device__ __forceinline__ float rfl_f(float v) {
    return __uint_as_float(__builtin_amdgcn_readfirstlane(__float_as_uint(v)));
}
static __device__ __forceinline__ unsigned short f2bf(float v) {
    __hip_bfloat16 h = __float2bfloat16(v);
    return *reinterpret_cast<unsigned short*>(&h);
}

// ---------------- Kernel 1: router LIF + spike mean, fused with weight prep ---------
__global__ void k_lif_prep(const float* __restrict__ x, float* __restrict__ mean_spk,
                           const float* __restrict__ w1, const float* __restrict__ b1,
                           const float* __restrict__ g1, const float* __restrict__ be1,
                           const float* __restrict__ w2, const float* __restrict__ b2,
                           const float* __restrict__ g2, const float* __restrict__ be2,
                           unsigned short* __restrict__ wb,
                           float* __restrict__ fb1, float* __restrict__ fb2) {
    if (blockIdx.x >= BB * CC) {
        int idx = (blockIdx.x - BB * CC) * 256 + threadIdx.x;
        if (idx < EE * CC * CC) {
            int e = idx >> 12, rem = idx & 4095;
            int o = rem >> 6;
            float s1 = g1[e * 64 + o] * RSQ;
            float s2 = g2[e * 64 + o] * RSQ;
            wb[(e * 2 + 0) * 4096 + rem] = f2bf(w1[idx] * s1);
            wb[(e * 2 + 1) * 4096 + rem] = f2bf(w2[idx] * s2);
        }
        if (idx < EE * CC) {
            fb1[idx] = b1[idx] * (g1[idx] * RSQ) + be1[idx];
            fb2[idx] = b2[idx] * (g2[idx] * RSQ) + be2[idx];
        }
        return;
    }
    int bc = blockIdx.x;
    int b = bc >> 6, c = bc & 63;
    int tid = threadIdx.x;
    const size_t tstride = (size_t)BB * CC * PP;
    const float* xp = x + ((size_t)b * CC + c) * PP + tid * 4;
    f32x4 v = {0.f, 0.f, 0.f, 0.f};
    float cnt[4];
    #pragma unroll
    for (int t = 0; t < 4; ++t) {
        f32x4 xt = *(const f32x4*)(xp + t * tstride);
        float cc = 0.f;
        #pragma unroll
        for (int r = 0; r < 4; ++r) {
            v[r] += (xt[r] - v[r]) * 0.5f;
            bool s = v[r] >= 1.f;
            cc += s ? 1.f : 0.f;
            v[r] = s ? 0.f : v[r];
        }
        cnt[t] = cc;
    }
    __shared__ float red[4][4];
    int lane = tid & 63, wv = tid >> 6;
    #pragma unroll
    for (int off = 32; off > 0; off >>= 1) {
        cnt[0] += __shfl_down(cnt[0], off, 64);
        cnt[1] += __shfl_down(cnt[1], off, 64);
        cnt[2] += __shfl_down(cnt[2], off, 64);
        cnt[3] += __shfl_down(cnt[3], off, 64);
    }
    if (lane == 0) { red[wv][0] = cnt[0]; red[wv][1] = cnt[1]; red[wv][2] = cnt[2]; red[wv][3] = cnt[3]; }
    __syncthreads();
    if (tid < 4) {
        float s = red[0][tid] + red[1][tid] + red[2][tid] + red[3][tid];
        mean_spk[((size_t)tid * BB + b) * CC + c] = s * (1.f / 1024.f);
    }
}

// ---- packed spike bytes (bit BIT) -> short8 bf16 {0,1} frag ----
template <int BIT>
static __device__ __forceinline__ short8 unpack8(unsigned d0, unsigned d1) {
    const unsigned am = 0x00010001u << BIT;
    const unsigned mu = 0x3F80u >> BIT;
    union { unsigned u[4]; short8 s; } cv;
    unsigned t;
    t = __builtin_amdgcn_perm(0u, d0, 0x0C010C00u) & am; cv.u[0] = t * mu;
    t = __builtin_amdgcn_perm(0u, d0, 0x0C030C02u) & am; cv.u[1] = t * mu;
    t = __builtin_amdgcn_perm(0u, d1, 0x0C010C00u) & am; cv.u[2] = t * mu;
    t = __builtin_amdgcn_perm(0u, d1, 0x0C030C02u) & am; cv.u[3] = t * mu;
    return cv.s;
}

// ---------------- Kernel 2: experts via MFMA, fine-grain ch+px-split waves ----------
// Block = 64 px of one token, 4 waves. Wave (c,z): px chunk c (32px), out-ch half z
// (32 ch), BOTH experts. acc[2][2]x2 = 32 VGPR; x held in regs stage->bias.
// mfma_f32_16x16x32_bf16 (A=spikes, B=weights):
//   A[i][k]: i=lane%16 (px), k=8*(lane/16)+j; D[i][j]: j=lane%16 (=out ch), i=4*(lane/16)+r (=px)
__global__ void __launch_bounds__(256) __attribute__((amdgpu_waves_per_eu(4, 8))) k_experts(
    const float* __restrict__ x, const float* __restrict__ mean_spk,
    const float* __restrict__ rw, const float* __restrict__ rb,
    const float* __restrict__ rg, const float* __restrict__ rbe,
    const unsigned short* __restrict__ wb,
    const float* __restrict__ fb1, const float* __restrict__ fb2,
    float* __restrict__ out)
{
    __shared__ unsigned char s1[64 * 72];   // spike bytes (bit0=A, bit1=B), block-shared
    __shared__ unsigned char s2[64 * 72];

    int blk = blockIdx.x;
    int n = blk >> 4;
    int slab = blk & 15;                // 64-px slab within token
    int tid = threadIdx.x;
    int wv = tid >> 6;
    int lane = tid & 63;
    int l16 = lane & 15;
    int g = lane >> 4;
    int z = wv & 1;                     // out-ch half
    int c = wv >> 1;                    // px chunk within slab
    int P0loc = c << 5;                 // local px base (0 or 32)
    int P0 = (slab << 6) + P0loc;       // px base within token

    const float* __restrict__ xn = x + (size_t)n * (CC * PP);

    // ---- issue router loads ----
    int re = lane >> 3, rcb = (lane & 7) << 3;
    f32x4 msv0 = *(const f32x4*)(mean_spk + n * CC + rcb);
    f32x4 msv1 = *(const f32x4*)(mean_spk + n * CC + rcb + 4);
    f32x4 rwv0 = *(const f32x4*)(rw + re * CC + rcb);
    f32x4 rwv1 = *(const f32x4*)(rw + re * CC + rcb + 4);

    // ---- issue ALL stage x loads (D-mapping: ch=l16+16tn+32z, px=P0+tm*16+g*4+r) ----
    f32x4 xs[2][2];
    #pragma unroll
    for (int tn = 0; tn < 2; ++tn)
        #pragma unroll
        for (int tm = 0; tm < 2; ++tm)
            xs[tn][tm] = *(const f32x4*)(xn + (size_t)(l16 + 16 * tn + 32 * z) * PP
                                         + P0 + tm * 16 + g * 4);

    // ---- router compute: logits, top2 (softmax /sum skipped: scale-invariant) ----
    float part = 0.f;
    #pragma unroll
    for (int r = 0; r < 4; ++r) part = fmaf(msv0[r], rwv0[r], part);
    #pragma unroll
    for (int r = 0; r < 4; ++r) part = fmaf(msv1[r], rwv1[r], part);
    part += __shfl_xor(part, 1, 64);
    part += __shfl_xor(part, 2, 64);
    part += __shfl_xor(part, 4, 64);
    float logit = (part + rb[re]) * (rg[re] * RSQ) + rbe[re];
    float l[EE];
    #pragma unroll
    for (int j = 0; j < EE; ++j) l[j] = __shfl(logit, j << 3, 64);
    float m = l[0];
    #pragma unroll
    for (int e = 1; e < EE; ++e) m = fmaxf(m, l[e]);
    float pr[EE];
    #pragma unroll
    for (int e = 0; e < EE; ++e) pr[e] = __expf(l[e] - m);
    int e1i = 0; float v1 = pr[0];
    #pragma unroll
    for (int e = 1; e < EE; ++e) { if (pr[e] > v1) { v1 = pr[e]; e1i = e; } }
    int e2i = (e1i == 0) ? 1 : 0; float v2 = (e1i == 0) ? pr[1] : pr[0];
    #pragma unroll
    for (int e = 0; e < EE; ++e) { if (e != e1i && pr[e] > v2) { v2 = pr[e]; e2i = e; } }
    float wAv = v1 / (v1 + v2), wBv = v2 / (v1 + v2);

    int e1 = __builtin_amdgcn_readfirstlane(e1i);
    int e2 = __builtin_amdgcn_readfirstlane(e2i);
    wAv = rfl_f(wAv); wBv = rfl_f(wBv);
    float tauA = (float)(1.5 + 2.5 * (double)e1 / 7.0);
    float tauB = (float)(1.5 + 2.5 * (double)e2 / 7.0);
    float wsum1 = 1.f + wAv + wBv;
    float kx = wsum1 / wAv;             // wAv >= 0.5; fold x*wsum1 into accA

    const unsigned short* wbA = wb + e1 * 8192;
    const unsigned short* wbB = wb + e2 * 8192;
    int ch0 = l16 + 32 * z;             // tn=0 channel; tn=1 is ch0+16

    // ---- issue conv1 weight loads + bias consts (hide under mask build) ----
    short8 wfA[4], wfB[4];
    #pragma unroll
    for (int ks = 0; ks < 2; ++ks)
        #pragma unroll
        for (int tn = 0; tn < 2; ++tn) {
            wfA[ks * 2 + tn] = *(const short8*)(wbA + ((ch0 + 16 * tn) * 64 + ks * 32 + g * 8));
            wfB[ks * 2 + tn] = *(const short8*)(wbB + ((ch0 + 16 * tn) * 64 + ks * 32 + g * 8));
        }
    float b1A[2], b2A[2], b1B[2], b2B[2];
    #pragma unroll
    for (int tn = 0; tn < 2; ++tn) {
        b1A[tn] = fb1[e1 * 64 + ch0 + 16 * tn];
        b2A[tn] = fb2[e1 * 64 + ch0 + 16 * tn];
        b1B[tn] = fb1[e2 * 64 + ch0 + 16 * tn];
        b2B[tn] = fb2[e2 * 64 + ch0 + 16 * tn];
    }

    // ---- mask build + s1 byte scatter (px=P0loc+tm*16+g*4+r, ch=ch0+16tn) ----
    #pragma unroll
    for (int tn = 0; tn < 2; ++tn) {
        int ch = ch0 + 16 * tn;
        #pragma unroll
        for (int tm = 0; tm < 2; ++tm) {
            int px = P0loc + tm * 16 + g * 4;
            #pragma unroll
            for (int r = 0; r < 4; ++r) {
                float xv = xs[tn][tm][r];
                s1[(px + r) * 72 + ch] =
                    (unsigned char)((xv >= tauA ? 1u : 0u) | (xv >= tauB ? 2u : 0u));
            }
        }
    }
    __syncthreads();

    f32x4 accA[2][2], accB[2][2];
    #pragma unroll
    for (int tm = 0; tm < 2; ++tm)
        #pragma unroll
        for (int tn = 0; tn < 2; ++tn) {
            accA[tm][tn] = (f32x4){0.f, 0.f, 0.f, 0.f};
            accB[tm][tn] = (f32x4){0.f, 0.f, 0.f, 0.f};
        }

    // ---- conv1: A-frags from s1 (all 64 in-ch), B = this wave's 32 out-ch ----
    #pragma unroll
    for (int ks = 0; ks < 2; ++ks)
        #pragma unroll
        for (int tm = 0; tm < 2; ++tm) {
            const unsigned* mp = (const unsigned*)(s1 + (P0loc + tm * 16 + l16) * 72 + ks * 32 + g * 8);
            unsigned d0 = mp[0], d1 = mp[1];
            short8 aA = unpack8<0>(d0, d1);
            accA[tm][0] = __builtin_amdgcn_mfma_f32_16x16x32_bf16(aA, wfA[ks * 2 + 0], accA[tm][0], 0, 0, 0);
            accA[tm][1] = __builtin_amdgcn_mfma_f32_16x16x32_bf16(aA, wfA[ks * 2 + 1], accA[tm][1], 0, 0, 0);
            short8 aB = unpack8<1>(d0, d1);
            accB[tm][0] = __builtin_amdgcn_mfma_f32_16x16x32_bf16(aB, wfB[ks * 2 + 0], accB[tm][0], 0, 0, 0);
            accB[tm][1] = __builtin_amdgcn_mfma_f32_16x16x32_bf16(aB, wfB[ks * 2 + 1], accB[tm][1], 0, 0, 0);
        }

    // ---- prefetch conv2 weights (latency hides under bias phase) ----
    #pragma unroll
    for (int ks = 0; ks < 2; ++ks)
        #pragma unroll
        for (int tn = 0; tn < 2; ++tn) {
            wfA[ks * 2 + tn] = *(const short8*)(wbA + 4096 + ((ch0 + 16 * tn) * 64 + ks * 32 + g * 8));
            wfB[ks * 2 + tn] = *(const short8*)(wbB + 4096 + ((ch0 + 16 * tn) * 64 + ks * 32 + g * 8));
        }

    // ---- bias: zero loads (x in regs); write s2 bits; fold f1+f2+x*kx into acc ----
    #pragma unroll
    for (int tn = 0; tn < 2; ++tn) {
        int ch = ch0 + 16 * tn;
        #pragma unroll
        for (int tm = 0; tm < 2; ++tm) {
            int px = P0loc + tm * 16 + g * 4;
            #pragma unroll
            for (int r = 0; r < 4; ++r) {
                float xvr = xs[tn][tm][r];
                float bnA = accA[tm][tn][r] + b1A[tn];
                float x2A = xvr + bnA;
                float bnB = accB[tm][tn][r] + b1B[tn];
                float x2B = xvr + bnB;
                s2[(px + r) * 72 + ch] =
                    (unsigned char)((x2A >= tauA ? 1u : 0u) | (x2B >= tauB ? 2u : 0u));
                accA[tm][tn][r] = bnA + b2A[tn] + xvr * kx;
                accB[tm][tn][r] = bnB + b2B[tn];
            }
        }
    }
    __syncthreads();

    // ---- conv2: A-frags from s2 ----
    #pragma unroll
    for (int ks = 0; ks < 2; ++ks)
        #pragma unroll
        for (int tm = 0; tm < 2; ++tm) {
            const unsigned* mp = (const unsigned*)(s2 + (P0loc + tm * 16 + l16) * 72 + ks * 32 + g * 8);
            unsigned d0 = mp[0], d1 = mp[1];
            short8 aA = unpack8<0>(d0, d1);
            accA[tm][0] = __builtin_amdgcn_mfma_f32_16x16x32_bf16(aA, wfA[ks * 2 + 0], accA[tm][0], 0, 0, 0);
            accA[tm][1] = __builtin_amdgcn_mfma_f32_16x16x32_bf16(aA, wfA[ks * 2 + 1], accA[tm][1], 0, 0, 0);
            short8 aB = unpack8<1>(d0, d1);
            accB[tm][0] = __builtin_amdgcn_mfma_f32_16x16x32_bf16(aB, wfB[ks * 2 + 0], accB[tm][0], 0, 0, 0);
            accB[tm][1] = __builtin_amdgcn_mfma_f32_16x16x32_bf16(aB, wfB[ks * 2 + 1], accB[tm][1], 0, 0, 0);
        }

    // ---- final: out = wA*accA + wB*accB (x folded); 4 f32x4 stores, no loads ----
    float* __restrict__ on = out + (size_t)n * (CC * PP);
    #pragma unroll
    for (int tn = 0; tn < 2; ++tn) {
        int ch = ch0 + 16 * tn;
        #pragma unroll
        for (int tm = 0; tm < 2; ++tm) {
            f32x4 o;
            #pragma unroll
            for (int r = 0; r < 4; ++r)
                o[r] = fmaf(wAv, accA[tm][tn][r], wBv * accB[tm][tn][r]);
            *(f32x4*)(on + (size_t)ch * PP + P0 + tm * 16 + g * 4) = o;
        }
    }
}

extern "C" void kernel_launch(void* const* d_in, const int* in_sizes, int n_in,
                              void* d_out, int out_size, void* d_ws, size_t ws_size,
                              hipStream_t stream) {
    const float* x   = (const float*)d_in[0];
    const float* w1  = (const float*)d_in[1];
    const float* b1  = (const float*)d_in[2];
    const float* g1  = (const float*)d_in[3];
    const float* be1 = (const float*)d_in[4];
    const float* w2  = (const float*)d_in[5];
    const float* b2  = (const float*)d_in[6];
    const float* g2  = (const float*)d_in[7];
    const float* be2 = (const float*)d_in[8];
    const float* rw  = (const float*)d_in[9];
    const float* rb  = (const float*)d_in[10];
    const float* rg  = (const float*)d_in[11];
    const float* rbe = (const float*)d_in[12];
    float* out = (float*)d_out;
    float* ws  = (float*)d_ws;

    float* mean_spk     = ws;                                 // 16384 floats
    unsigned short* wb  = (unsigned short*)(ws + 16384);      // 65536 ushorts = 32768 floats
    float* fb1          = ws + 49152;                         // 512
    float* fb2          = ws + 49664;                         // 512

    hipLaunchKernelGGL(k_lif_prep, dim3(BB * CC + 128), dim3(256), 0, stream,
                       x, mean_spk, w1, b1, g1, be1, w2, b2, g2, be2, wb, fb1, fb2);
    hipLaunchKernelGGL(k_experts, dim3(NN * 16), dim3(256), 0, stream,
                       x, mean_spk, rw, rb, rg, rbe, wb, fb1, fb2, out);
}

// Round 12
// 48.702 us; speedup vs baseline: 1.2880x; 1.2880x over previous
//
#include <hip/hip_runtime.h>
#include <hip/hip_bf16.h>

#define TT 4
#define BB 64
#define CC 64
#define PP 1024
#define NN 256
#define EE 8

// 1/sqrt(1+1e-5)
#define RSQ 0.99999500003749975f

typedef __attribute__((ext_vector_type(8))) short short8;
typedef __attribute__((ext_vector_type(4))) float f32x4;

static __device__ __forceinline__ float rfl_f(float v) {
    return __uint_as_float(__builtin_amdgcn_readfirstlane(__float_as_uint(v)));
}
static __device__ __forceinline__ unsigned short f2bf(float v) {
    __hip_bfloat16 h = __float2bfloat16(v);
    return *reinterpret_cast<unsigned short*>(&h);
}

// ---------------- Kernel 1: router LIF + spike mean, fused with weight prep ---------
__global__ void k_lif_prep(const float* __restrict__ x, float* __restrict__ mean_spk,
                           const float* __restrict__ w1, const float* __restrict__ b1,
                           const float* __restrict__ g1, const float* __restrict__ be1,
                           const float* __restrict__ w2, const float* __restrict__ b2,
                           const float* __restrict__ g2, const float* __restrict__ be2,
                           unsigned short* __restrict__ wb,
                           float* __restrict__ fb1, float* __restrict__ fb2) {
    if (blockIdx.x >= BB * CC) {
        int idx = (blockIdx.x - BB * CC) * 256 + threadIdx.x;
        if (idx < EE * CC * CC) {
            int e = idx >> 12, rem = idx & 4095;
            int o = rem >> 6;
            float s1 = g1[e * 64 + o] * RSQ;
            float s2 = g2[e * 64 + o] * RSQ;
            wb[(e * 2 + 0) * 4096 + rem] = f2bf(w1[idx] * s1);
            wb[(e * 2 + 1) * 4096 + rem] = f2bf(w2[idx] * s2);
        }
        if (idx < EE * CC) {
            fb1[idx] = b1[idx] * (g1[idx] * RSQ) + be1[idx];
            fb2[idx] = b2[idx] * (g2[idx] * RSQ) + be2[idx];
        }
        return;
    }
    int bc = blockIdx.x;
    int b = bc >> 6, c = bc & 63;
    int tid = threadIdx.x;
    const size_t tstride = (size_t)BB * CC * PP;
    const float* xp = x + ((size_t)b * CC + c) * PP + tid * 4;
    f32x4 v = {0.f, 0.f, 0.f, 0.f};
    float cnt[4];
    #pragma unroll
    for (int t = 0; t < 4; ++t) {
        f32x4 xt = *(const f32x4*)(xp + t * tstride);
        float cc = 0.f;
        #pragma unroll
        for (int r = 0; r < 4; ++r) {
            v[r] += (xt[r] - v[r]) * 0.5f;
            bool s = v[r] >= 1.f;
            cc += s ? 1.f : 0.f;
            v[r] = s ? 0.f : v[r];
        }
        cnt[t] = cc;
    }
    __shared__ float red[4][4];
    int lane = tid & 63, wv = tid >> 6;
    #pragma unroll
    for (int off = 32; off > 0; off >>= 1) {
        cnt[0] += __shfl_down(cnt[0], off, 64);
        cnt[1] += __shfl_down(cnt[1], off, 64);
        cnt[2] += __shfl_down(cnt[2], off, 64);
        cnt[3] += __shfl_down(cnt[3], off, 64);
    }
    if (lane == 0) { red[wv][0] = cnt[0]; red[wv][1] = cnt[1]; red[wv][2] = cnt[2]; red[wv][3] = cnt[3]; }
    __syncthreads();
    if (tid < 4) {
        float s = red[0][tid] + red[1][tid] + red[2][tid] + red[3][tid];
        mean_spk[((size_t)tid * BB + b) * CC + c] = s * (1.f / 1024.f);
    }
}

// ---- packed spike bytes (bit BIT) -> short8 bf16 {0,1} frag ----
template <int BIT>
static __device__ __forceinline__ short8 unpack8(unsigned d0, unsigned d1) {
    const unsigned am = 0x00010001u << BIT;
    const unsigned mu = 0x3F80u >> BIT;
    union { unsigned u[4]; short8 s; } cv;
    unsigned t;
    t = __builtin_amdgcn_perm(0u, d0, 0x0C010C00u) & am; cv.u[0] = t * mu;
    t = __builtin_amdgcn_perm(0u, d0, 0x0C030C02u) & am; cv.u[1] = t * mu;
    t = __builtin_amdgcn_perm(0u, d1, 0x0C010C00u) & am; cv.u[2] = t * mu;
    t = __builtin_amdgcn_perm(0u, d1, 0x0C030C02u) & am; cv.u[3] = t * mu;
    return cv.s;
}

// ---------------- Kernel 2: experts via MFMA, pipelined 4-slab blocks ----------------
// Block = token-quarter (256 px), 4 waves = ch-quarters. Wave: 64px slab x 16 out-ch x
// both experts, looped over 4 slabs with double-buffered s1/s2 and next-slab x loads
// issued at loop top (latency hides under conv1+bias). Weights (2exp x 2conv) + router
// loaded ONCE per block. One __syncthreads per slab.
// mfma(A=spikes,B=weights): A[i][k]: i=lane%16 (px-row), k=8*(lane/16)+j;
// D[i][j]: j=lane%16 (=out ch), i=4*(lane/16)+r (=px).
__global__ void __launch_bounds__(256) __attribute__((amdgpu_waves_per_eu(4, 8))) k_experts(
    const float* __restrict__ x, const float* __restrict__ mean_spk,
    const float* __restrict__ rw, const float* __restrict__ rb,
    const float* __restrict__ rg, const float* __restrict__ rbe,
    const unsigned short* __restrict__ wb,
    const float* __restrict__ fb1, const float* __restrict__ fb2,
    float* __restrict__ out)
{
    __shared__ unsigned char s1[2][64 * 72];   // spike bytes (bit0=A, bit1=B), dbuf
    __shared__ unsigned char s2[2][64 * 72];

    int blk = blockIdx.x;
    int n = blk >> 2;
    int q = blk & 3;
    int tid = threadIdx.x;
    int z = tid >> 6;                   // wave = out-ch quarter
    int lane = tid & 63;
    int l16 = lane & 15;
    int g = lane >> 4;
    int Q0 = q << 8;                    // quarter px base
    int ch = z * 16 + l16;              // this lane's out-ch (D: j = l16)

    const float* __restrict__ xn = x + (size_t)n * (CC * PP);

    // ---- issue router loads ----
    int re = lane >> 3, rcb = (lane & 7) << 3;
    f32x4 msv0 = *(const f32x4*)(mean_spk + n * CC + rcb);
    f32x4 msv1 = *(const f32x4*)(mean_spk + n * CC + rcb + 4);
    f32x4 rwv0 = *(const f32x4*)(rw + re * CC + rcb);
    f32x4 rwv1 = *(const f32x4*)(rw + re * CC + rcb + 4);

    // ---- issue slab-0 x loads (ch = z*16+l16, px = Q0 + tm*16 + 4g) ----
    f32x4 xsbuf[2][4];
    {
        const float* xc = xn + (size_t)ch * PP + Q0 + 4 * g;
        #pragma unroll
        for (int tm = 0; tm < 4; ++tm)
            xsbuf[0][tm] = *(const f32x4*)(xc + tm * 16);
    }

    // ---- router compute (overlaps in-flight loads) ----
    float part = 0.f;
    #pragma unroll
    for (int r = 0; r < 4; ++r) part = fmaf(msv0[r], rwv0[r], part);
    #pragma unroll
    for (int r = 0; r < 4; ++r) part = fmaf(msv1[r], rwv1[r], part);
    part += __shfl_xor(part, 1, 64);
    part += __shfl_xor(part, 2, 64);
    part += __shfl_xor(part, 4, 64);
    float logit = (part + rb[re]) * (rg[re] * RSQ) + rbe[re];
    float l[EE];
    #pragma unroll
    for (int j = 0; j < EE; ++j) l[j] = __shfl(logit, j << 3, 64);
    float m = l[0];
    #pragma unroll
    for (int e = 1; e < EE; ++e) m = fmaxf(m, l[e]);
    float pr[EE];
    #pragma unroll
    for (int e = 0; e < EE; ++e) pr[e] = __expf(l[e] - m);
    int e1i = 0; float v1 = pr[0];
    #pragma unroll
    for (int e = 1; e < EE; ++e) { if (pr[e] > v1) { v1 = pr[e]; e1i = e; } }
    int e2i = (e1i == 0) ? 1 : 0; float v2 = (e1i == 0) ? pr[1] : pr[0];
    #pragma unroll
    for (int e = 0; e < EE; ++e) { if (e != e1i && pr[e] > v2) { v2 = pr[e]; e2i = e; } }
    float wAv = v1 / (v1 + v2), wBv = v2 / (v1 + v2);

    int e1 = __builtin_amdgcn_readfirstlane(e1i);
    int e2 = __builtin_amdgcn_readfirstlane(e2i);
    wAv = rfl_f(wAv); wBv = rfl_f(wBv);
    float tauA = (float)(1.5 + 2.5 * (double)e1 / 7.0);
    float tauB = (float)(1.5 + 2.5 * (double)e2 / 7.0);
    float kx = (1.f + wAv + wBv) / wAv;   // wAv >= 0.5; fold x*wsum1 into accA

    const unsigned short* wbA = wb + e1 * 8192;
    const unsigned short* wbB = wb + e2 * 8192;

    // ---- all 4 weight-frag sets, loaded ONCE per block (32 VGPR) ----
    short8 w1A[2], w1B[2], w2A[2], w2B[2];
    #pragma unroll
    for (int ks = 0; ks < 2; ++ks) {
        int wo = ch * 64 + ks * 32 + g * 8;
        w1A[ks] = *(const short8*)(wbA + wo);
        w1B[ks] = *(const short8*)(wbB + wo);
        w2A[ks] = *(const short8*)(wbA + 4096 + wo);
        w2B[ks] = *(const short8*)(wbB + 4096 + wo);
    }
    float b1A = fb1[e1 * 64 + ch];
    float b1B = fb1[e2 * 64 + ch];
    float cst = wAv * fb2[e1 * 64 + ch] + wBv * fb2[e2 * 64 + ch];  // epilogue const

    // ---- mask slab 0 -> s1[0] ----
    #pragma unroll
    for (int tm = 0; tm < 4; ++tm)
        #pragma unroll
        for (int r = 0; r < 4; ++r) {
            float xv = xsbuf[0][tm][r];
            s1[0][(tm * 16 + 4 * g + r) * 72 + ch] =
                (unsigned char)((xv >= tauA ? 1u : 0u) | (xv >= tauB ? 2u : 0u));
        }
    __syncthreads();

    float* __restrict__ on = out + (size_t)n * (CC * PP);

    // ---- pipelined slab loop: one __syncthreads per slab ----
    #pragma unroll
    for (int s = 0; s < 4; ++s) {
        const int par = s & 1, nxt = par ^ 1;

        // issue next slab's x loads (in flight under conv1 + bias)
        if (s < 3) {
            const float* xc = xn + (size_t)ch * PP + Q0 + (s + 1) * 64 + 4 * g;
            #pragma unroll
            for (int tm = 0; tm < 4; ++tm)
                xsbuf[nxt][tm] = *(const f32x4*)(xc + tm * 16);
        }

        // conv1(s)
        f32x4 accA[4], accB[4];
        #pragma unroll
        for (int tm = 0; tm < 4; ++tm) {
            accA[tm] = (f32x4){0.f, 0.f, 0.f, 0.f};
            accB[tm] = (f32x4){0.f, 0.f, 0.f, 0.f};
        }
        #pragma unroll
        for (int ks = 0; ks < 2; ++ks)
            #pragma unroll
            for (int tm = 0; tm < 4; ++tm) {
                const unsigned* mp = (const unsigned*)(&s1[par][0] + (tm * 16 + l16) * 72 + ks * 32 + g * 8);
                unsigned d0 = mp[0], d1 = mp[1];
                short8 aA = unpack8<0>(d0, d1);
                accA[tm] = __builtin_amdgcn_mfma_f32_16x16x32_bf16(aA, w1A[ks], accA[tm], 0, 0, 0);
                short8 aB = unpack8<1>(d0, d1);
                accB[tm] = __builtin_amdgcn_mfma_f32_16x16x32_bf16(aB, w1B[ks], accB[tm], 0, 0, 0);
            }

        // bias(s): held x; write s2 bits; fold b1 and x*kx into acc
        #pragma unroll
        for (int tm = 0; tm < 4; ++tm)
            #pragma unroll
            for (int r = 0; r < 4; ++r) {
                float xv = xsbuf[par][tm][r];
                float bnA = accA[tm][r] + b1A;
                float bnB = accB[tm][r] + b1B;
                s2[par][(tm * 16 + 4 * g + r) * 72 + ch] =
                    (unsigned char)(((xv + bnA) >= tauA ? 1u : 0u) | ((xv + bnB) >= tauB ? 2u : 0u));
                accA[tm][r] = fmaf(xv, kx, bnA);
                accB[tm][r] = bnB;
            }

        // mask(s+1) -> s1[nxt]
        if (s < 3) {
            #pragma unroll
            for (int tm = 0; tm < 4; ++tm)
                #pragma unroll
                for (int r = 0; r < 4; ++r) {
                    float xv = xsbuf[nxt][tm][r];
                    s1[nxt][(tm * 16 + 4 * g + r) * 72 + ch] =
                        (unsigned char)((xv >= tauA ? 1u : 0u) | (xv >= tauB ? 2u : 0u));
                }
        }
        __syncthreads();

        // conv2(s)
        #pragma unroll
        for (int ks = 0; ks < 2; ++ks)
            #pragma unroll
            for (int tm = 0; tm < 4; ++tm) {
                const unsigned* mp = (const unsigned*)(&s2[par][0] + (tm * 16 + l16) * 72 + ks * 32 + g * 8);
                unsigned d0 = mp[0], d1 = mp[1];
                short8 aA = unpack8<0>(d0, d1);
                accA[tm] = __builtin_amdgcn_mfma_f32_16x16x32_bf16(aA, w2A[ks], accA[tm], 0, 0, 0);
                short8 aB = unpack8<1>(d0, d1);
                accB[tm] = __builtin_amdgcn_mfma_f32_16x16x32_bf16(aB, w2B[ks], accB[tm], 0, 0, 0);
            }

        // store(s): out = wA*accA + wB*accB + cst (x & b2 folded)
        #pragma unroll
        for (int tm = 0; tm < 4; ++tm) {
            f32x4 o;
            #pragma unroll
            for (int r = 0; r < 4; ++r)
                o[r] = fmaf(wAv, accA[tm][r], fmaf(wBv, accB[tm][r], cst));
            *(f32x4*)(on + (size_t)ch * PP + Q0 + s * 64 + tm * 16 + 4 * g) = o;
        }
    }
}

extern "C" void kernel_launch(void* const* d_in, const int* in_sizes, int n_in,
                              void* d_out, int out_size, void* d_ws, size_t ws_size,
                              hipStream_t stream) {
    const float* x   = (const float*)d_in[0];
    const float* w1  = (const float*)d_in[1];
    const float* b1  = (const float*)d_in[2];
    const float* g1  = (const float*)d_in[3];
    const float* be1 = (const float*)d_in[4];
    const float* w2  = (const float*)d_in[5];
    const float* b2  = (const float*)d_in[6];
    const float* g2  = (const float*)d_in[7];
    const float* be2 = (const float*)d_in[8];
    const float* rw  = (const float*)d_in[9];
    const float* rb  = (const float*)d_in[10];
    const float* rg  = (const float*)d_in[11];
    const float* rbe = (const float*)d_in[12];
    float* out = (float*)d_out;
    float* ws  = (float*)d_ws;

    float* mean_spk     = ws;                                 // 16384 floats
    unsigned short* wb  = (unsigned short*)(ws + 16384);      // 65536 ushorts = 32768 floats
    float* fb1          = ws + 49152;                         // 512
    float* fb2          = ws + 49664;                         // 512

    hipLaunchKernelGGL(k_lif_prep, dim3(BB * CC + 128), dim3(256), 0, stream,
                       x, mean_spk, w1, b1, g1, be1, w2, b2, g2, be2, wb, fb1, fb2);
    hipLaunchKernelGGL(k_experts, dim3(NN * 4), dim3(256), 0, stream,
                       x, mean_spk, rw, rb, rg, rbe, wb, fb1, fb2, out);
}

// Round 13
// 46.685 us; speedup vs baseline: 1.3437x; 1.0432x over previous
//
#include <hip/hip_runtime.h>
#include <hip/hip_bf16.h>

#define TT 4
#define BB 64
#define CC 64
#define PP 1024
#define NN 256
#define EE 8

// 1/sqrt(1+1e-5)
#define RSQ 0.99999500003749975f

typedef __attribute__((ext_vector_type(8))) short short8;
typedef __attribute__((ext_vector_type(4))) float f32x4;

static __device__ __forceinline__ float rfl_f(float v) {
    return __uint_as_float(__builtin_amdgcn_readfirstlane(__float_as_uint(v)));
}
static __device__ __forceinline__ unsigned short f2bf(float v) {
    __hip_bfloat16 h = __float2bfloat16(v);
    return *reinterpret_cast<unsigned short*>(&h);
}

// ---------------- Kernel 1: router LIF + spike mean, fused with weight prep ---------
__global__ void k_lif_prep(const float* __restrict__ x, float* __restrict__ mean_spk,
                           const float* __restrict__ w1, const float* __restrict__ b1,
                           const float* __restrict__ g1, const float* __restrict__ be1,
                           const float* __restrict__ w2, const float* __restrict__ b2,
                           const float* __restrict__ g2, const float* __restrict__ be2,
                           unsigned short* __restrict__ wb,
                           float* __restrict__ fb1, float* __restrict__ fb2) {
    if (blockIdx.x >= BB * CC) {
        int idx = (blockIdx.x - BB * CC) * 256 + threadIdx.x;
        if (idx < EE * CC * CC) {
            int e = idx >> 12, rem = idx & 4095;
            int o = rem >> 6;
            float s1 = g1[e * 64 + o] * RSQ;
            float s2 = g2[e * 64 + o] * RSQ;
            wb[(e * 2 + 0) * 4096 + rem] = f2bf(w1[idx] * s1);
            wb[(e * 2 + 1) * 4096 + rem] = f2bf(w2[idx] * s2);
        }
        if (idx < EE * CC) {
            fb1[idx] = b1[idx] * (g1[idx] * RSQ) + be1[idx];
            fb2[idx] = b2[idx] * (g2[idx] * RSQ) + be2[idx];
        }
        return;
    }
    int bc = blockIdx.x;
    int b = bc >> 6, c = bc & 63;
    int tid = threadIdx.x;
    const size_t tstride = (size_t)BB * CC * PP;
    const float* xp = x + ((size_t)b * CC + c) * PP + tid * 4;
    f32x4 v = {0.f, 0.f, 0.f, 0.f};
    float cnt[4];
    #pragma unroll
    for (int t = 0; t < 4; ++t) {
        f32x4 xt = *(const f32x4*)(xp + t * tstride);
        float cc = 0.f;
        #pragma unroll
        for (int r = 0; r < 4; ++r) {
            v[r] += (xt[r] - v[r]) * 0.5f;
            bool s = v[r] >= 1.f;
            cc += s ? 1.f : 0.f;
            v[r] = s ? 0.f : v[r];
        }
        cnt[t] = cc;
    }
    __shared__ float red[4][4];
    int lane = tid & 63, wv = tid >> 6;
    #pragma unroll
    for (int off = 32; off > 0; off >>= 1) {
        cnt[0] += __shfl_down(cnt[0], off, 64);
        cnt[1] += __shfl_down(cnt[1], off, 64);
        cnt[2] += __shfl_down(cnt[2], off, 64);
        cnt[3] += __shfl_down(cnt[3], off, 64);
    }
    if (lane == 0) { red[wv][0] = cnt[0]; red[wv][1] = cnt[1]; red[wv][2] = cnt[2]; red[wv][3] = cnt[3]; }
    __syncthreads();
    if (tid < 4) {
        float s = red[0][tid] + red[1][tid] + red[2][tid] + red[3][tid];
        mean_spk[((size_t)tid * BB + b) * CC + c] = s * (1.f / 1024.f);
    }
}

// ---------------- Kernel 2: experts via MFMA, bf16-plane LDS (zero unpack) ----------
// Block = token-quarter (256 px), 4 waves = ch-quarters, 4-slab loop.
// Spikes stored as ready-to-MFMA bf16 planes: s1p/s2p[expert][64 px][72 ch] ushort
// (144-B rows: 16B-aligned b128 reads, 2-way banks = free). Producers write 0x3F80/0
// ushorts; conv A-frags are direct ds_read_b128 -- the unpack VALU is gone.
// Single-buffered planes, 2 barriers/slab:
//   conv1(s) | BAR | bias(s)->s2p, mask(s+1)->s1p | BAR | conv2(s), store(s)
// mfma(A=spikes,B=weights): A[i][k]: i=lane%16 (px-row), k=8*(lane/16)+j;
// D[i][j]: j=lane%16 (=out ch), i=4*(lane/16)+r (=px).
__global__ void __launch_bounds__(256) __attribute__((amdgpu_waves_per_eu(4, 8))) k_experts(
    const float* __restrict__ x, const float* __restrict__ mean_spk,
    const float* __restrict__ rw, const float* __restrict__ rb,
    const float* __restrict__ rg, const float* __restrict__ rbe,
    const unsigned short* __restrict__ wb,
    const float* __restrict__ fb1, const float* __restrict__ fb2,
    float* __restrict__ out)
{
    __shared__ unsigned short s1p[2][64 * 72];   // bf16 spike planes, expert A/B
    __shared__ unsigned short s2p[2][64 * 72];

    int blk = blockIdx.x;
    int n = blk >> 2;
    int q = blk & 3;
    int tid = threadIdx.x;
    int z = tid >> 6;                   // wave = out-ch quarter
    int lane = tid & 63;
    int l16 = lane & 15;
    int g = lane >> 4;
    int Q0 = q << 8;                    // quarter px base
    int ch = z * 16 + l16;              // this lane's out-ch (D: j = l16)

    const float* __restrict__ xn = x + (size_t)n * (CC * PP);

    // ---- issue router loads ----
    int re = lane >> 3, rcb = (lane & 7) << 3;
    f32x4 msv0 = *(const f32x4*)(mean_spk + n * CC + rcb);
    f32x4 msv1 = *(const f32x4*)(mean_spk + n * CC + rcb + 4);
    f32x4 rwv0 = *(const f32x4*)(rw + re * CC + rcb);
    f32x4 rwv1 = *(const f32x4*)(rw + re * CC + rcb + 4);

    // ---- issue slab-0 x loads (ch = z*16+l16, px = Q0 + tm*16 + 4g) ----
    f32x4 xsbuf[2][4];
    {
        const float* xc = xn + (size_t)ch * PP + Q0 + 4 * g;
        #pragma unroll
        for (int tm = 0; tm < 4; ++tm)
            xsbuf[0][tm] = *(const f32x4*)(xc + tm * 16);
    }

    // ---- router compute (overlaps in-flight loads) ----
    float part = 0.f;
    #pragma unroll
    for (int r = 0; r < 4; ++r) part = fmaf(msv0[r], rwv0[r], part);
    #pragma unroll
    for (int r = 0; r < 4; ++r) part = fmaf(msv1[r], rwv1[r], part);
    part += __shfl_xor(part, 1, 64);
    part += __shfl_xor(part, 2, 64);
    part += __shfl_xor(part, 4, 64);
    float logit = (part + rb[re]) * (rg[re] * RSQ) + rbe[re];
    float l[EE];
    #pragma unroll
    for (int j = 0; j < EE; ++j) l[j] = __shfl(logit, j << 3, 64);
    float m = l[0];
    #pragma unroll
    for (int e = 1; e < EE; ++e) m = fmaxf(m, l[e]);
    float pr[EE];
    #pragma unroll
    for (int e = 0; e < EE; ++e) pr[e] = __expf(l[e] - m);
    int e1i = 0; float v1 = pr[0];
    #pragma unroll
    for (int e = 1; e < EE; ++e) { if (pr[e] > v1) { v1 = pr[e]; e1i = e; } }
    int e2i = (e1i == 0) ? 1 : 0; float v2 = (e1i == 0) ? pr[1] : pr[0];
    #pragma unroll
    for (int e = 0; e < EE; ++e) { if (e != e1i && pr[e] > v2) { v2 = pr[e]; e2i = e; } }
    float wAv = v1 / (v1 + v2), wBv = v2 / (v1 + v2);

    int e1 = __builtin_amdgcn_readfirstlane(e1i);
    int e2 = __builtin_amdgcn_readfirstlane(e2i);
    wAv = rfl_f(wAv); wBv = rfl_f(wBv);
    float tauA = (float)(1.5 + 2.5 * (double)e1 / 7.0);
    float tauB = (float)(1.5 + 2.5 * (double)e2 / 7.0);
    float kx = (1.f + wAv + wBv) / wAv;   // wAv >= 0.5; fold x*wsum1 into accA

    const unsigned short* wbA = wb + e1 * 8192;
    const unsigned short* wbB = wb + e2 * 8192;

    // ---- all 4 weight-frag sets, loaded ONCE per block ----
    short8 w1A[2], w1B[2], w2A[2], w2B[2];
    #pragma unroll
    for (int ks = 0; ks < 2; ++ks) {
        int wo = ch * 64 + ks * 32 + g * 8;
        w1A[ks] = *(const short8*)(wbA + wo);
        w1B[ks] = *(const short8*)(wbB + wo);
        w2A[ks] = *(const short8*)(wbA + 4096 + wo);
        w2B[ks] = *(const short8*)(wbB + 4096 + wo);
    }
    float b1A = fb1[e1 * 64 + ch];
    float b1B = fb1[e2 * 64 + ch];
    float cst = wAv * fb2[e1 * 64 + ch] + wBv * fb2[e2 * 64 + ch];  // epilogue const

    // ---- mask slab 0 -> s1 planes ----
    #pragma unroll
    for (int tm = 0; tm < 4; ++tm)
        #pragma unroll
        for (int r = 0; r < 4; ++r) {
            float xv = xsbuf[0][tm][r];
            int px = tm * 16 + 4 * g + r;
            s1p[0][px * 72 + ch] = (xv >= tauA) ? (unsigned short)0x3F80 : (unsigned short)0;
            s1p[1][px * 72 + ch] = (xv >= tauB) ? (unsigned short)0x3F80 : (unsigned short)0;
        }
    __syncthreads();

    float* __restrict__ on = out + (size_t)n * (CC * PP);

    // ---- pipelined slab loop: 2 barriers per slab ----
    #pragma unroll
    for (int s = 0; s < 4; ++s) {
        const int par = s & 1, nxt = par ^ 1;

        // issue next slab's x loads (in flight under conv1 + bias)
        if (s < 3) {
            const float* xc = xn + (size_t)ch * PP + Q0 + (s + 1) * 64 + 4 * g;
            #pragma unroll
            for (int tm = 0; tm < 4; ++tm)
                xsbuf[nxt][tm] = *(const f32x4*)(xc + tm * 16);
        }

        // conv1(s): direct b128 A-frags from s1 planes; acc init = b1 (C-init free)
        f32x4 accA[4], accB[4];
        #pragma unroll
        for (int tm = 0; tm < 4; ++tm) {
            accA[tm] = (f32x4){b1A, b1A, b1A, b1A};
            accB[tm] = (f32x4){b1B, b1B, b1B, b1B};
        }
        #pragma unroll
        for (int ks = 0; ks < 2; ++ks)
            #pragma unroll
            for (int tm = 0; tm < 4; ++tm) {
                const unsigned short* rowp = &s1p[0][(tm * 16 + l16) * 72 + ks * 32 + g * 8];
                short8 aA = *(const short8*)rowp;
                short8 aB = *(const short8*)(rowp + 64 * 72);
                accA[tm] = __builtin_amdgcn_mfma_f32_16x16x32_bf16(aA, w1A[ks], accA[tm], 0, 0, 0);
                accB[tm] = __builtin_amdgcn_mfma_f32_16x16x32_bf16(aB, w1B[ks], accB[tm], 0, 0, 0);
            }
        __syncthreads();   // BAR1: all conv1 reads done; planes may be overwritten

        // bias(s): write s2 planes; fold x*kx into accA (b1 already in acc)
        #pragma unroll
        for (int tm = 0; tm < 4; ++tm)
            #pragma unroll
            for (int r = 0; r < 4; ++r) {
                float xv = xsbuf[par][tm][r];
                float bnA = accA[tm][r];
                float bnB = accB[tm][r];
                int px = tm * 16 + 4 * g + r;
                s2p[0][px * 72 + ch] = ((xv + bnA) >= tauA) ? (unsigned short)0x3F80 : (unsigned short)0;
                s2p[1][px * 72 + ch] = ((xv + bnB) >= tauB) ? (unsigned short)0x3F80 : (unsigned short)0;
                accA[tm][r] = fmaf(xv, kx, bnA);
            }

        // mask(s+1) -> s1 planes
        if (s < 3) {
            #pragma unroll
            for (int tm = 0; tm < 4; ++tm)
                #pragma unroll
                for (int r = 0; r < 4; ++r) {
                    float xv = xsbuf[nxt][tm][r];
                    int px = tm * 16 + 4 * g + r;
                    s1p[0][px * 72 + ch] = (xv >= tauA) ? (unsigned short)0x3F80 : (unsigned short)0;
                    s1p[1][px * 72 + ch] = (xv >= tauB) ? (unsigned short)0x3F80 : (unsigned short)0;
                }
        }
        __syncthreads();   // BAR2: s2(s) ready; s1(s+1) ready

        // conv2(s): direct b128 A-frags from s2 planes
        #pragma unroll
        for (int ks = 0; ks < 2; ++ks)
            #pragma unroll
            for (int tm = 0; tm < 4; ++tm) {
                const unsigned short* rowp = &s2p[0][(tm * 16 + l16) * 72 + ks * 32 + g * 8];
                short8 aA = *(const short8*)rowp;
                short8 aB = *(const short8*)(rowp + 64 * 72);
                accA[tm] = __builtin_amdgcn_mfma_f32_16x16x32_bf16(aA, w2A[ks], accA[tm], 0, 0, 0);
                accB[tm] = __builtin_amdgcn_mfma_f32_16x16x32_bf16(aB, w2B[ks], accB[tm], 0, 0, 0);
            }

        // store(s): out = wA*accA + wB*accB + cst (x & b2 folded)
        #pragma unroll
        for (int tm = 0; tm < 4; ++tm) {
            f32x4 o;
            #pragma unroll
            for (int r = 0; r < 4; ++r)
                o[r] = fmaf(wAv, accA[tm][r], fmaf(wBv, accB[tm][r], cst));
            *(f32x4*)(on + (size_t)ch * PP + Q0 + s * 64 + tm * 16 + 4 * g) = o;
        }
    }
}

extern "C" void kernel_launch(void* const* d_in, const int* in_sizes, int n_in,
                              void* d_out, int out_size, void* d_ws, size_t ws_size,
                              hipStream_t stream) {
    const float* x   = (const float*)d_in[0];
    const float* w1  = (const float*)d_in[1];
    const float* b1  = (const float*)d_in[2];
    const float* g1  = (const float*)d_in[3];
    const float* be1 = (const float*)d_in[4];
    const float* w2  = (const float*)d_in[5];
    const float* b2  = (const float*)d_in[6];
    const float* g2  = (const float*)d_in[7];
    const float* be2 = (const float*)d_in[8];
    const float* rw  = (const float*)d_in[9];
    const float* rb  = (const float*)d_in[10];
    const float* rg  = (const float*)d_in[11];
    const float* rbe = (const float*)d_in[12];
    float* out = (float*)d_out;
    float* ws  = (float*)d_ws;

    float* mean_spk     = ws;                                 // 16384 floats
    unsigned short* wb  = (unsigned short*)(ws + 16384);      // 65536 ushorts = 32768 floats
    float* fb1          = ws + 49152;                         // 512
    float* fb2          = ws + 49664;                         // 512

    hipLaunchKernelGGL(k_lif_prep, dim3(BB * CC + 128), dim3(256), 0, stream,
                       x, mean_spk, w1, b1, g1, be1, w2, b2, g2, be2, wb, fb1, fb2);
    hipLaunchKernelGGL(k_experts, dim3(NN * 4), dim3(256), 0, stream,
                       x, mean_spk, rw, rb, rg, rbe, wb, fb1, fb2, out);
}